// Round 9
// baseline (2440.940 us; speedup 1.0000x reference)
//
#include <hip/hip_runtime.h>

// PhysicsRULModel fully-fused kernel for MI355X (gfx950).  R8.
// grid = 256 x 256 (1 block/CU, 4 waves). Recurrence in f16 via
// v_dot2_f32_f16 (fp32 accumulate): one lane holds ALL THREE matrices'
// quarter-rows (Whh0, Wih1, Whh1 = 96 h2 VGPRs), so 4 unified waves do both
// layers -> no wave-split, no g1ih handoff, no skew, h double-buffered.
// h state in LDS as h2 (quarter = 2 ds_read_b128): main-loop LDS instrs
// drop ~64 -> ~20 per step; barrier is 4-wave not 8-wave.
// QSUM leaves all 4 gate sums in every quad lane -> no sel4/DPP-gather;
// each lane does full gate activations (c0/c1 fp32 in regs, replicated
// per quad). h packs via RNE casts (pkrtz's RTZ bias would accumulate
// through the 2048-step health cumsum). h1ring stays fp32 -> epilogue
// (R7's, remapped to 4 waves x 8 positions, CH=32) is full precision.
// Iteration u: L0 step u from h0(u-1); L1 step u-1 from h0(u-1), h1(u-2).
// Epilogue at u==1 (mod 32), t0=u-33 (L1 done through t=u-2).

#define Bn 256
#define Tn 2048
#define Hn 64
#define CH 32
#define NT 256

typedef _Float16 h2 __attribute__((ext_vector_type(2)));
union HU { int i; h2 h; };

__device__ __forceinline__ h2 I2H(int v) { HU u; u.i = v; return u.h; }
__device__ __forceinline__ float rcpf_(float x) { return __builtin_amdgcn_rcpf(x); }
__device__ __forceinline__ float sigf_(float x) { return rcpf_(1.f + __expf(-x)); }
__device__ __forceinline__ float tanhf2_(float x) {
    float e = __expf(2.0f * x);
    return 1.0f - 2.0f * rcpf_(e + 1.0f);
}
// D = S0.h[0]*S1.h[0] + S0.h[1]*S1.h[1] + D   (VOP3P, fp32 accumulate)
__device__ __forceinline__ void dot2(float& acc, h2 w, h2 x) {
    asm("v_dot2_f32_f16 %0, %1, %2, %0" : "+v"(acc) : "v"(w), "v"(x));
}
#define DPPF(v, ctrl) __int_as_float(__builtin_amdgcn_update_dpp(0, __float_as_int(v), (ctrl), 0xF, 0xF, true))
#define QSUM(v) { v += DPPF(v, 0xB1); v += DPPF(v, 0x4E); }
#define DOT4(acc, w_, x_) { acc = fmaf((w_).x,(x_).x, fmaf((w_).y,(x_).y, fmaf((w_).z,(x_).z, fmaf((w_).w,(x_).w, acc)))); }
#define LGKM0() asm volatile("s_waitcnt lgkmcnt(0)" ::: "memory")

// full-wave sum (64 lanes)
__device__ __forceinline__ float wsum64_(float v) {
    v += DPPF(v, 0xB1); v += DPPF(v, 0x4E);
    v += __shfl_xor(v, 4); v += __shfl_xor(v, 8);
    v += __shfl_xor(v, 16); v += __shfl_xor(v, 32);
    return v;
}

__global__ __launch_bounds__(256, 1)
void fused_rul_kernel(
    const float* __restrict__ ts,   const float* __restrict__ sf,
    const float* __restrict__ Wih0, const float* __restrict__ Whh0,
    const float* __restrict__ bih0, const float* __restrict__ bhh0,
    const float* __restrict__ Wih1, const float* __restrict__ Whh1,
    const float* __restrict__ bih1, const float* __restrict__ bhh1,
    const float* __restrict__ seW1, const float* __restrict__ seb1,
    const float* __restrict__ seW2, const float* __restrict__ seb2,
    const float* __restrict__ pbW1, const float* __restrict__ pbb1,
    const float* __restrict__ pbW2, const float* __restrict__ pbb2,
    const float* __restrict__ pbW3, const float* __restrict__ pbb3,
    const float* __restrict__ drW1, const float* __restrict__ drb1,
    const float* __restrict__ drW2, const float* __restrict__ drb2,
    const float* __restrict__ drW3, const float* __restrict__ drb3,
    const float* __restrict__ ruW1, const float* __restrict__ rub1,
    const float* __restrict__ ruW2, const float* __restrict__ rub2,
    float* __restrict__ out)
{
    const int tid  = threadIdx.x;
    const int b    = blockIdx.x;
    const int lane = tid & 63;
    const int w    = tid >> 6;                       // wave 0..3
    const int q    = lane & 3;                       // 16-col quarter
    const int s    = (w << 4) | (lane >> 2);         // unit 0..63

    // ---- LDS ----
    __shared__ __align__(16) h2 h0h[2][32];          // h0 state (f16), dbuf
    __shared__ __align__(16) h2 h1h[2][32];          // h1 state (f16), dbuf
    __shared__ __align__(16) float h1ring[CH][Hn];   // fp32, slot = t & 31
    __shared__ float tempc[CH];
    __shared__ __align__(16) float ssb[CH][32];
    __shared__ __align__(16) float se1b[4][32];      // wave-private
    __shared__ __align__(16) float dr1b[4][Hn];      // wave-private
    __shared__ float degb[CH];
    __shared__ float hltb[CH];
    __shared__ __align__(16) float seW1L[32 * 68];
    __shared__ __align__(16) float seW2L[32 * 36];
    __shared__ __align__(16) float drW1L[64 * 36];
    __shared__ __align__(16) float drW2L[32 * 68];
    __shared__ __align__(16) float ruW1L[32 * 36];
    __shared__ float seb1L[32], seb2L[32], drb1L[64], drb2L[32], drW3L[32];
    __shared__ float rub1L[32], ruW2L[32];
    __shared__ float phys_s[4];
    __shared__ float drb3_s, rub2_s;

    // ---- cooperative LDS weight staging ----
    for (int i = tid; i < 32 * 64; i += NT) { int rr = i >> 6, c = i & 63; seW1L[rr * 68 + c] = seW1[i]; }
    for (int i = tid; i < 32 * 32; i += NT) { int rr = i >> 5, c = i & 31; seW2L[rr * 36 + c] = seW2[i]; }
    for (int i = tid; i < 64 * 35; i += NT) { int rr = i / 35, c = i % 35; drW1L[rr * 36 + c] = drW1[i]; }
    for (int i = tid; i < 32 * 64; i += NT) { int rr = i >> 6, c = i & 63; drW2L[rr * 68 + c] = drW2[i]; }
    for (int i = tid; i < 32 * 33; i += NT) { int rr = i / 33, c = i % 33; ruW1L[rr * 36 + c] = ruW1[i]; }
    if (tid < 32) {
        seb1L[tid] = seb1[tid]; seb2L[tid] = seb2[tid]; drb2L[tid] = drb2[tid];
        drW3L[tid] = drW3[tid]; rub1L[tid] = rub1[tid]; ruW2L[tid] = ruW2[tid];
    }
    if (tid < 64) drb1L[tid] = drb1[tid];
    if (tid == 0) { drb3_s = drb3[0]; rub2_s = rub2[0]; }

    // ---- physics branch (tiny MLP, thread 0) ----
    if (tid == 0) {
        float p1[32];
        for (int o = 0; o < 32; ++o) {
            float a = pbb1[o];
            for (int k = 0; k < 3; ++k) a += pbW1[o * 3 + k] * sf[b * 3 + k];
            p1[o] = fmaxf(a, 0.f);
        }
        float p2[16];
        for (int o = 0; o < 16; ++o) {
            float a = pbb2[o];
            for (int k = 0; k < 32; ++k) a += pbW2[o * 32 + k] * p1[k];
            p2[o] = fmaxf(a, 0.f);
        }
        float Ea = pbb3[0], lA = pbb3[1];
        for (int k = 0; k < 16; ++k) { Ea += pbW3[k] * p2[k]; lA += pbW3[16 + k] * p2[k]; }
        phys_s[0] = __expf(lA);
        phys_s[1] = -Ea * 1000.0f / 8.314f;
        phys_s[2] = Ea;
        phys_s[3] = lA;
    }

    // ---- LSTM weights into f16 VGPRs: 3 matrices x 4 gate-rows x quarter ----
    h2 wh0[32], wi1[32], wh1[32];
    float b0g[4], b1g[4], wxa[4], wxb[4];
    #pragma unroll
    for (int g = 0; g < 4; ++g) {
        const int row = (g << 6) + s;
        const float* r0 = Whh0 + row * 64 + (q << 4);
        const float* r1 = Wih1 + row * 64 + (q << 4);
        const float* r2 = Whh1 + row * 64 + (q << 4);
        #pragma unroll
        for (int k = 0; k < 8; ++k) {
            h2 a, bb, c;
            a.x = (_Float16)r0[2 * k]; a.y = (_Float16)r0[2 * k + 1];
            bb.x = (_Float16)r1[2 * k]; bb.y = (_Float16)r1[2 * k + 1];
            c.x = (_Float16)r2[2 * k]; c.y = (_Float16)r2[2 * k + 1];
            wh0[g * 8 + k] = a; wi1[g * 8 + k] = bb; wh1[g * 8 + k] = c;
        }
        b0g[g] = bih0[row] + bhh0[row];
        b1g[g] = bih1[row] + bhh1[row];
        wxa[g] = Wih0[row * 2 + 0];
        wxb[g] = Wih0[row * 2 + 1];
    }

    float c0 = 0.f, c1 = 0.f;       // cell states (replicated per quad)
    float hst = 1.0f;               // health state (wave 0)
    float xprev = 0.f;
    if (tid < 64) { ((int*)h0h)[tid] = 0; ((int*)h1h)[tid] = 0; }
    __syncthreads();

    const float* tsb  = ts + (size_t)b * Tn * 2;
    float* outR = out + (size_t)b * Tn;
    float* outD = out + (size_t)Bn * Tn + (size_t)b * Tn;
    float* outH = out + 2 * (size_t)Bn * Tn + (size_t)b * Tn;

    #pragma unroll 1
    for (int u = 0; u <= Tn + 1; ++u) {
        float2 xv = make_float2(0.f, 0.f);
        if (u < Tn) xv = *(const float2*)(tsb + 2 * u);

        // ================= epilogue: chunk [u-33, u-2] =================
        if ((u & (CH - 1)) == 1 && u >= 33) {
            const int tbase = u - 33;
            const int hh = (tid >> 5) & 1;
            const int jj = tid & 31;
            const int j64 = lane;

            // ---- Stage A: se1 + se2 (wave-private), 8 positions ----
            {
                float4 w1[8], w2[4];
                const float4* p1 = (const float4*)(seW1L + jj * 68 + hh * 32);
                #pragma unroll
                for (int k = 0; k < 8; ++k) w1[k] = p1[k];
                const float4* p2 = (const float4*)(seW2L + jj * 36 + hh * 16);
                #pragma unroll
                for (int k = 0; k < 4; ++k) w2[k] = p2[k];
                const float b1 = seb1L[jj], b2 = seb2L[jj];
                #pragma unroll
                for (int i = 0; i < 8; ++i) {
                    const int pos = w + 4 * i;
                    const float4* ha = (const float4*)(&h1ring[pos][hh * 32]);
                    float acc = 0.f;
                    #pragma unroll
                    for (int k = 0; k < 8; ++k) { float4 hv = ha[k]; DOT4(acc, w1[k], hv); }
                    acc += __shfl_xor(acc, 32);
                    float se1v = fmaxf(acc + b1, 0.f);
                    if (hh == 0) se1b[w][jj] = se1v;
                    LGKM0();
                    const float4* sa = (const float4*)(&se1b[w][hh * 16]);
                    float a2 = 0.f;
                    #pragma unroll
                    for (int k = 0; k < 4; ++k) { float4 xv4 = sa[k]; DOT4(a2, w2[k], xv4); }
                    a2 += __shfl_xor(a2, 32);
                    if (hh == 0) ssb[pos][jj] = a2 + b2;
                }
            }
            LGKM0();
            // ---- Stage B: dr1 + dr2 + dr3 (wave-private), 8 positions ----
            {
                float4 wd1[9];
                const float4* p1 = (const float4*)(drW1L + j64 * 36);
                #pragma unroll
                for (int k = 0; k < 9; ++k) wd1[k] = p1[k];
                float4 wd2[8];
                const float4* p2 = (const float4*)(drW2L + jj * 68 + hh * 32);
                #pragma unroll
                for (int k = 0; k < 8; ++k) wd2[k] = p2[k];
                const float bb1 = drb1L[j64], bb2 = drb2L[jj], w3 = drW3L[jj];
                const float ea_ = phys_s[2], la_ = phys_s[3];
                #pragma unroll
                for (int i = 0; i < 8; ++i) {
                    const int pos = w + 4 * i;
                    const float tmp_ = tempc[pos];
                    const float4* xa = (const float4*)(&ssb[pos][0]);
                    float acc = 0.f;
                    #pragma unroll
                    for (int k = 0; k < 8; ++k) { float4 xv4 = xa[k]; DOT4(acc, wd1[k], xv4); }
                    acc += wd1[8].x * tmp_ + wd1[8].y * ea_ + wd1[8].z * la_;
                    dr1b[w][j64] = fmaxf(acc + bb1, 0.f);
                    LGKM0();
                    const float4* da = (const float4*)(&dr1b[w][hh * 32]);
                    float a2 = 0.f;
                    #pragma unroll
                    for (int k = 0; k < 8; ++k) { float4 xv4 = da[k]; DOT4(a2, wd2[k], xv4); }
                    a2 += __shfl_xor(a2, 32);
                    float tt = w3 * fmaxf(a2 + bb2, 0.f);
                    float sum = wsum64_(tt);
                    float deg = 0.5f * sum + drb3_s;
                    if (lane == 0) { degb[pos] = deg; outD[tbase + pos] = deg; }
                }
            }
            __syncthreads();
            // ---- Stage C: health scan (wave 0, clamp-affine parallel scan) ----
            if (w == 0) {
                const int t = lane;
                const float Af = phys_s[0], ne = phys_s[1];
                float a_ = 0.f, l_ = -1e30f, u_ = 1e30f;
                if (t < 32) {
                    float dg = degb[t];
                    float tK = tempc[t] + 273.15f;
                    float arr = Af * __expf(ne * rcpf_(tK));
                    a_ = -(0.7f * dg + 0.3f * arr);
                    l_ = 0.f; u_ = 1.f;
                }
                #pragma unroll
                for (int d = 1; d < 32; d <<= 1) {
                    float pa = __shfl_up(a_, d);
                    float pl = __shfl_up(l_, d);
                    float pu = __shfl_up(u_, d);
                    if (t >= d && t < 32) {
                        float na = pa + a_;
                        float nl = fminf(fmaxf(pl + a_, l_), u_);
                        float nu = fminf(fmaxf(pu + a_, l_), u_);
                        a_ = na; l_ = nl; u_ = nu;
                    }
                }
                float hval = fminf(fmaxf(hst + a_, l_), u_);
                if (t < 32) { hltb[t] = hval; outH[tbase + t] = hval; }
                float a31 = __shfl(a_, 31), l31 = __shfl(l_, 31), u31 = __shfl(u_, 31);
                hst = fminf(fmaxf(hst + a31, l31), u31);
            }
            __syncthreads();
            // ---- Stage D: rul head, 8 positions ----
            {
                float4 wr4[4];
                const float4* p1 = (const float4*)(ruW1L + jj * 36 + hh * 16);
                #pragma unroll
                for (int k = 0; k < 4; ++k) wr4[k] = p1[k];
                const float whc = ruW1L[jj * 36 + 32];
                const float br = rub1L[jj], w2r = ruW2L[jj];
                #pragma unroll
                for (int i = 0; i < 8; ++i) {
                    const int pos = w + 4 * i;
                    const float4* xa = (const float4*)(&ssb[pos][hh * 16]);
                    float acc = 0.f;
                    #pragma unroll
                    for (int k = 0; k < 4; ++k) { float4 xv4 = xa[k]; DOT4(acc, wr4[k], xv4); }
                    acc += __shfl_xor(acc, 32);
                    float aa = acc + br + whc * hltb[pos];
                    float pp = w2r * fmaxf(aa, 0.f);
                    float sum = wsum64_(pp);
                    if (lane == 0) outR[tbase + pos] = fmaxf(0.5f * sum + rub2_s, 0.f);
                }
            }
        }

        // ================= LSTM step: L0(u) + L1(u-1) =================
        if (u <= Tn) {
            const int rb0 = (u + 1) & 1;     // h0(u-1)
            const int rb1 = u & 1;           // h1(u-2)
            const int4* p0 = (const int4*)&h0h[rb0][q << 3];
            int4 Aa = p0[0], Ab = p0[1];
            const int4* p1 = (const int4*)&h1h[rb1][q << 3];
            int4 Ba = p1[0], Bb = p1[1];
            h2 hv[8] = { I2H(Aa.x), I2H(Aa.y), I2H(Aa.z), I2H(Aa.w),
                         I2H(Ab.x), I2H(Ab.y), I2H(Ab.z), I2H(Ab.w) };
            h2 gv[8] = { I2H(Ba.x), I2H(Ba.y), I2H(Ba.z), I2H(Ba.w),
                         I2H(Bb.x), I2H(Bb.y), I2H(Bb.z), I2H(Bb.w) };
            float s0 = 0.f, s1 = 0.f, s2 = 0.f, s3 = 0.f;   // L0 hh
            float u0 = 0.f, u1 = 0.f, u2 = 0.f, u3 = 0.f;   // L1 ih (on h0(u-1))
            float v0 = 0.f, v1 = 0.f, v2 = 0.f, v3 = 0.f;   // L1 hh
            #pragma unroll
            for (int k = 0; k < 8; ++k) {
                dot2(s0, wh0[k], hv[k]);  dot2(s1, wh0[8 + k], hv[k]);
                dot2(s2, wh0[16 + k], hv[k]); dot2(s3, wh0[24 + k], hv[k]);
                dot2(u0, wi1[k], hv[k]);  dot2(u1, wi1[8 + k], hv[k]);
                dot2(u2, wi1[16 + k], hv[k]); dot2(u3, wi1[24 + k], hv[k]);
                dot2(v0, wh1[k], gv[k]);  dot2(v1, wh1[8 + k], gv[k]);
                dot2(v2, wh1[16 + k], gv[k]); dot2(v3, wh1[24 + k], gv[k]);
            }
            QSUM(s0); QSUM(s1); QSUM(s2); QSUM(s3);
            QSUM(u0); QSUM(u1); QSUM(u2); QSUM(u3);
            QSUM(v0); QSUM(v1); QSUM(v2); QSUM(v3);
            if (u < Tn) {
                float pi = fmaf(wxa[0], xv.x, fmaf(wxb[0], xv.y, s0 + b0g[0]));
                float pf = fmaf(wxa[1], xv.x, fmaf(wxb[1], xv.y, s1 + b0g[1]));
                float pg = fmaf(wxa[2], xv.x, fmaf(wxb[2], xv.y, s2 + b0g[2]));
                float po = fmaf(wxa[3], xv.x, fmaf(wxb[3], xv.y, s3 + b0g[3]));
                float ai = sigf_(pi), af = sigf_(pf), ag = tanhf2_(pg), ao = sigf_(po);
                c0 = fmaf(af, c0, ai * ag);
                float h0n = ao * tanhf2_(c0);
                float prt = __shfl_xor(h0n, 4);
                if ((lane & 7) == 0) {          // q==0 && s even
                    h2 pk; pk.x = (_Float16)h0n; pk.y = (_Float16)prt;   // RNE
                    h0h[u & 1][(w << 3) | (lane >> 3)] = pk;
                }
            }
            if (u >= 1) {
                float pi = u0 + v0 + b1g[0];
                float pf = u1 + v1 + b1g[1];
                float pg = u2 + v2 + b1g[2];
                float po = u3 + v3 + b1g[3];
                float ai = sigf_(pi), af = sigf_(pf), ag = tanhf2_(pg), ao = sigf_(po);
                c1 = fmaf(af, c1, ai * ag);
                float h1n = ao * tanhf2_(c1);
                float prt = __shfl_xor(h1n, 4);
                if ((lane & 7) == 0) {
                    h2 pk; pk.x = (_Float16)h1n; pk.y = (_Float16)prt;   // RNE
                    h1h[(u + 1) & 1][(w << 3) | (lane >> 3)] = pk;
                }
                if (q == 1) h1ring[(u - 1) & (CH - 1)][s] = h1n;   // fp32 for epilogue
                if (tid == 0) tempc[(u - 1) & (CH - 1)] = xprev;
            }
            xprev = xv.x;
        }
        __syncthreads();
    }
}

extern "C" void kernel_launch(void* const* d_in, const int* in_sizes, int n_in,
                              void* d_out, int out_size, void* d_ws, size_t ws_size,
                              hipStream_t stream) {
    const float* ts   = (const float*)d_in[0];
    const float* sf   = (const float*)d_in[1];
    const float* Wih0 = (const float*)d_in[2];
    const float* Whh0 = (const float*)d_in[3];
    const float* bih0 = (const float*)d_in[4];
    const float* bhh0 = (const float*)d_in[5];
    const float* Wih1 = (const float*)d_in[6];
    const float* Whh1 = (const float*)d_in[7];
    const float* bih1 = (const float*)d_in[8];
    const float* bhh1 = (const float*)d_in[9];
    const float* seW1 = (const float*)d_in[10];
    const float* seb1 = (const float*)d_in[11];
    const float* seW2 = (const float*)d_in[12];
    const float* seb2 = (const float*)d_in[13];
    const float* pbW1 = (const float*)d_in[14];
    const float* pbb1 = (const float*)d_in[15];
    const float* pbW2 = (const float*)d_in[16];
    const float* pbb2 = (const float*)d_in[17];
    const float* pbW3 = (const float*)d_in[18];
    const float* pbb3 = (const float*)d_in[19];
    const float* drW1 = (const float*)d_in[20];
    const float* drb1 = (const float*)d_in[21];
    const float* drW2 = (const float*)d_in[22];
    const float* drb2 = (const float*)d_in[23];
    const float* drW3 = (const float*)d_in[24];
    const float* drb3 = (const float*)d_in[25];
    const float* ruW1 = (const float*)d_in[26];
    const float* rub1 = (const float*)d_in[27];
    const float* ruW2 = (const float*)d_in[28];
    const float* rub2 = (const float*)d_in[29];
    float* out = (float*)d_out;

    fused_rul_kernel<<<dim3(Bn), dim3(NT), 0, stream>>>(
        ts, sf, Wih0, Whh0, bih0, bhh0, Wih1, Whh1, bih1, bhh1,
        seW1, seb1, seW2, seb2, pbW1, pbb1, pbW2, pbb2, pbW3, pbb3,
        drW1, drb1, drW2, drb2, drW3, drb3, ruW1, rub1, ruW2, rub2, out);
}

// Round 10
// 1806.496 us; speedup vs baseline: 1.3512x; 1.3512x over previous
//
#include <hip/hip_runtime.h>

// PhysicsRULModel fully-fused kernel for MI355X (gfx950).  R9.
// grid = 256 x 512 (1 block/CU, 8 waves). Producer-consumer wave split:
//   waves 0-3: f16 LSTM recurrence (R8 structure: one lane holds all three
//     matrices' quarter-rows as h2; v_dot2_f32_f16, fp32 accum, QSUM leaves
//     all 4 gate sums in every quad lane; no wave handoff).
//   waves 4-7: epilogue engine. Chunk k's MLP chain runs DURING chunk k+1's
//     LSTM, sliced 1 position-stage per iteration. Each SIMD hosts 1 LSTM
//     wave + 1 epilogue wave -> epilogue fills LSTM stall slots (m114).
// Both paths are separate loops executing IDENTICAL barrier counts
// (1 pre-loop + 2081 in-loop); s_barrier pairs waves by arrival count.
// Epilogue weights resident in epilogue-wave VGPRs as f16 (loaded once from
// global; no LDS weight tables). h1ring/ssb/se1b/dr1b in f16 (halved LDS
// traffic); deg/health/rul arithmetic fp32. tempc/h1ring are 64-slot rings
// (double-chunk): LSTM writes the half the epilogue is NOT reading.
// Epilogue schedule within chunk c (phase p = 0..31, iterations
// u = 32c+33 .. 32c+64): p<8 stage A (se1+se2) for pos ew+4p; p in [8,16)
// stage B (dr1+dr2+dr3 -> degb, outD); p==16 health scan (wave 4,
// clamp-affine parallel scan); p in [17,25) stage D (rul -> outR); idle after.

#define Bn 256
#define Tn 2048
#define Hn 64
#define CH 32
#define NT 512

typedef _Float16 h2 __attribute__((ext_vector_type(2)));
union HU { int i; h2 h; };

__device__ __forceinline__ h2 I2H(int v) { HU u; u.i = v; return u.h; }
__device__ __forceinline__ h2 F2H2(float a, float b) { h2 r; r.x = (_Float16)a; r.y = (_Float16)b; return r; }
__device__ __forceinline__ float rcpf_(float x) { return __builtin_amdgcn_rcpf(x); }
__device__ __forceinline__ float sigf_(float x) { return rcpf_(1.f + __expf(-x)); }
__device__ __forceinline__ float tanhf2_(float x) {
    float e = __expf(2.0f * x);
    return 1.0f - 2.0f * rcpf_(e + 1.0f);
}
__device__ __forceinline__ void dot2(float& acc, h2 w, h2 x) {
    asm("v_dot2_f32_f16 %0, %1, %2, %0" : "+v"(acc) : "v"(w), "v"(x));
}
#define DPPF(v, ctrl) __int_as_float(__builtin_amdgcn_update_dpp(0, __float_as_int(v), (ctrl), 0xF, 0xF, true))
#define QSUM(v) { v += DPPF(v, 0xB1); v += DPPF(v, 0x4E); }
#define LGKM0() asm volatile("s_waitcnt lgkmcnt(0)" ::: "memory")

__device__ __forceinline__ float wsum64_(float v) {
    v += DPPF(v, 0xB1); v += DPPF(v, 0x4E);
    v += __shfl_xor(v, 4); v += __shfl_xor(v, 8);
    v += __shfl_xor(v, 16); v += __shfl_xor(v, 32);
    return v;
}

__global__ __launch_bounds__(512, 1)
void fused_rul_kernel(
    const float* __restrict__ ts,   const float* __restrict__ sf,
    const float* __restrict__ Wih0, const float* __restrict__ Whh0,
    const float* __restrict__ bih0, const float* __restrict__ bhh0,
    const float* __restrict__ Wih1, const float* __restrict__ Whh1,
    const float* __restrict__ bih1, const float* __restrict__ bhh1,
    const float* __restrict__ seW1, const float* __restrict__ seb1,
    const float* __restrict__ seW2, const float* __restrict__ seb2,
    const float* __restrict__ pbW1, const float* __restrict__ pbb1,
    const float* __restrict__ pbW2, const float* __restrict__ pbb2,
    const float* __restrict__ pbW3, const float* __restrict__ pbb3,
    const float* __restrict__ drW1, const float* __restrict__ drb1,
    const float* __restrict__ drW2, const float* __restrict__ drb2,
    const float* __restrict__ drW3, const float* __restrict__ drb3,
    const float* __restrict__ ruW1, const float* __restrict__ rub1,
    const float* __restrict__ ruW2, const float* __restrict__ rub2,
    float* __restrict__ out)
{
    const int tid  = threadIdx.x;
    const int b    = blockIdx.x;
    const int lane = tid & 63;
    const int w    = tid >> 6;                       // wave 0..7

    // ---- LDS (~12 KB) ----
    __shared__ __align__(16) h2 h0h[2][32];          // h0 state (f16), dbuf
    __shared__ __align__(16) h2 h1h[2][32];          // h1 state (f16), dbuf
    __shared__ __align__(16) _Float16 h1ring[64][Hn];// f16, slot = t & 63
    __shared__ float tempc[64];                      // slot = t & 63
    __shared__ __align__(16) _Float16 ssb[CH][32];   // f16 system_states
    __shared__ __align__(16) _Float16 se1b[4][32];   // wave-private f16
    __shared__ __align__(16) _Float16 dr1b[4][Hn];   // wave-private f16
    __shared__ float degb[CH];
    __shared__ float hltb[CH];
    __shared__ float phys_s[4];                      // [A, -Ea*1000/R, Ea, logA]

    float* outR = out + (size_t)b * Tn;
    float* outD = out + (size_t)Bn * Tn + (size_t)b * Tn;
    float* outH = out + 2 * (size_t)Bn * Tn + (size_t)b * Tn;

    if (w < 4) {
        // ================= LSTM path (waves 0-3) =================
        const int q = lane & 3;                      // 16-col quarter
        const int s = (w << 4) | (lane >> 2);        // unit 0..63

        h2 wh0[32], wi1[32], wh1[32];
        float b0g[4], b1g[4], wxa[4], wxb[4];
        #pragma unroll
        for (int g = 0; g < 4; ++g) {
            const int row = (g << 6) + s;
            const float* r0 = Whh0 + row * 64 + (q << 4);
            const float* r1 = Wih1 + row * 64 + (q << 4);
            const float* r2 = Whh1 + row * 64 + (q << 4);
            #pragma unroll
            for (int k = 0; k < 8; ++k) {
                wh0[g * 8 + k] = F2H2(r0[2 * k], r0[2 * k + 1]);
                wi1[g * 8 + k] = F2H2(r1[2 * k], r1[2 * k + 1]);
                wh1[g * 8 + k] = F2H2(r2[2 * k], r2[2 * k + 1]);
            }
            b0g[g] = bih0[row] + bhh0[row];
            b1g[g] = bih1[row] + bhh1[row];
            wxa[g] = Wih0[row * 2 + 0];
            wxb[g] = Wih0[row * 2 + 1];
        }
        float c0 = 0.f, c1 = 0.f;
        float xprev = 0.f;
        if (tid < 64) { ((int*)h0h)[tid] = 0; ((int*)h1h)[tid] = 0; }
        const float* tsb = ts + (size_t)b * Tn * 2;
        __syncthreads();                              // pre-loop barrier #0

        #pragma unroll 1
        for (int u = 0; u <= Tn + CH; ++u) {
            if (u <= Tn) {
                float2 xv = make_float2(0.f, 0.f);
                if (u < Tn) xv = *(const float2*)(tsb + 2 * u);
                const int rb0 = (u + 1) & 1;          // h0(u-1)
                const int rb1 = u & 1;                // h1(u-2)
                const int4* p0 = (const int4*)&h0h[rb0][q << 3];
                int4 Aa = p0[0], Ab = p0[1];
                const int4* p1 = (const int4*)&h1h[rb1][q << 3];
                int4 Ba = p1[0], Bb = p1[1];
                h2 hv[8] = { I2H(Aa.x), I2H(Aa.y), I2H(Aa.z), I2H(Aa.w),
                             I2H(Ab.x), I2H(Ab.y), I2H(Ab.z), I2H(Ab.w) };
                h2 gv[8] = { I2H(Ba.x), I2H(Ba.y), I2H(Ba.z), I2H(Ba.w),
                             I2H(Bb.x), I2H(Bb.y), I2H(Bb.z), I2H(Bb.w) };
                float s0 = 0.f, s1 = 0.f, s2 = 0.f, s3 = 0.f;
                float u0 = 0.f, u1 = 0.f, u2 = 0.f, u3 = 0.f;
                float v0 = 0.f, v1 = 0.f, v2 = 0.f, v3 = 0.f;
                #pragma unroll
                for (int k = 0; k < 8; ++k) {
                    dot2(s0, wh0[k], hv[k]);      dot2(s1, wh0[8 + k], hv[k]);
                    dot2(s2, wh0[16 + k], hv[k]); dot2(s3, wh0[24 + k], hv[k]);
                    dot2(u0, wi1[k], hv[k]);      dot2(u1, wi1[8 + k], hv[k]);
                    dot2(u2, wi1[16 + k], hv[k]); dot2(u3, wi1[24 + k], hv[k]);
                    dot2(v0, wh1[k], gv[k]);      dot2(v1, wh1[8 + k], gv[k]);
                    dot2(v2, wh1[16 + k], gv[k]); dot2(v3, wh1[24 + k], gv[k]);
                }
                QSUM(s0); QSUM(s1); QSUM(s2); QSUM(s3);
                QSUM(u0); QSUM(u1); QSUM(u2); QSUM(u3);
                QSUM(v0); QSUM(v1); QSUM(v2); QSUM(v3);
                if (u < Tn) {
                    float pi = fmaf(wxa[0], xv.x, fmaf(wxb[0], xv.y, s0 + b0g[0]));
                    float pf = fmaf(wxa[1], xv.x, fmaf(wxb[1], xv.y, s1 + b0g[1]));
                    float pg = fmaf(wxa[2], xv.x, fmaf(wxb[2], xv.y, s2 + b0g[2]));
                    float po = fmaf(wxa[3], xv.x, fmaf(wxb[3], xv.y, s3 + b0g[3]));
                    float ai = sigf_(pi), af = sigf_(pf), ag = tanhf2_(pg), ao = sigf_(po);
                    c0 = fmaf(af, c0, ai * ag);
                    float h0n = ao * tanhf2_(c0);
                    float prt = __shfl_xor(h0n, 4);
                    if ((lane & 7) == 0)
                        h0h[u & 1][(w << 3) | (lane >> 3)] = F2H2(h0n, prt);
                }
                if (u >= 1) {
                    float pi = u0 + v0 + b1g[0];
                    float pf = u1 + v1 + b1g[1];
                    float pg = u2 + v2 + b1g[2];
                    float po = u3 + v3 + b1g[3];
                    float ai = sigf_(pi), af = sigf_(pf), ag = tanhf2_(pg), ao = sigf_(po);
                    c1 = fmaf(af, c1, ai * ag);
                    float h1n = ao * tanhf2_(c1);
                    float prt = __shfl_xor(h1n, 4);
                    if ((lane & 7) == 0)
                        h1h[(u + 1) & 1][(w << 3) | (lane >> 3)] = F2H2(h1n, prt);
                    if (q == 1) h1ring[(u - 1) & 63][s] = (_Float16)h1n;
                    if (tid == 0) tempc[(u - 1) & 63] = xprev;
                }
                xprev = xv.x;
            }
            __syncthreads();
        }
    } else {
        // ================= epilogue path (waves 4-7) =================
        const int ew = w - 4;
        const int jj = lane & 31;
        const int hh = lane >> 5;

        // resident f16 weights, loaded once from GLOBAL
        h2 w1h[16], w2h[8], wd1h[16], wd2h[16], wr1h[8];
        float wt0, wt1, wt2, bb1, seb1r, seb2r, bb2, w3r, whc, brD, w2rD, drb3r, rub2r;
        {
            const float* r = seW1 + jj * 64 + hh * 32;
            #pragma unroll
            for (int k = 0; k < 16; ++k) w1h[k] = F2H2(r[2 * k], r[2 * k + 1]);
            r = seW2 + jj * 32 + hh * 16;
            #pragma unroll
            for (int k = 0; k < 8; ++k) w2h[k] = F2H2(r[2 * k], r[2 * k + 1]);
            r = drW1 + lane * 35;
            #pragma unroll
            for (int k = 0; k < 16; ++k) wd1h[k] = F2H2(r[2 * k], r[2 * k + 1]);
            wt0 = r[32]; wt1 = r[33]; wt2 = r[34];
            r = drW2 + jj * 64 + hh * 32;
            #pragma unroll
            for (int k = 0; k < 16; ++k) wd2h[k] = F2H2(r[2 * k], r[2 * k + 1]);
            r = ruW1 + jj * 33 + hh * 16;
            #pragma unroll
            for (int k = 0; k < 8; ++k) wr1h[k] = F2H2(r[2 * k], r[2 * k + 1]);
            seb1r = seb1[jj]; seb2r = seb2[jj];
            bb1 = drb1[lane]; bb2 = drb2[jj]; w3r = drW3[jj];
            whc = ruW1[jj * 33 + 32]; brD = rub1[jj]; w2rD = ruW2[jj];
            drb3r = drb3[0]; rub2r = rub2[0];
        }
        // physics branch (tiny MLP) on wave 4 lane 0
        if (tid == 256) {
            float p1[32];
            for (int o = 0; o < 32; ++o) {
                float a = pbb1[o];
                for (int k = 0; k < 3; ++k) a += pbW1[o * 3 + k] * sf[b * 3 + k];
                p1[o] = fmaxf(a, 0.f);
            }
            float p2[16];
            for (int o = 0; o < 16; ++o) {
                float a = pbb2[o];
                for (int k = 0; k < 32; ++k) a += pbW2[o * 32 + k] * p1[k];
                p2[o] = fmaxf(a, 0.f);
            }
            float Ea = pbb3[0], lA = pbb3[1];
            for (int k = 0; k < 16; ++k) { Ea += pbW3[k] * p2[k]; lA += pbW3[16 + k] * p2[k]; }
            phys_s[0] = __expf(lA);
            phys_s[1] = -Ea * 1000.0f / 8.314f;
            phys_s[2] = Ea;
            phys_s[3] = lA;
        }
        float hst = 1.0f;                             // health state (wave 4)
        __syncthreads();                              // pre-loop barrier #0

        #pragma unroll 1
        for (int u = 0; u <= Tn + CH; ++u) {
            if (u >= 33) {
                const int c = (u - 33) >> 5;          // chunk 0..63
                const int p = (u - 33) & 31;          // phase within chunk
                const int half = (c & 1) << 5;        // ring half for this chunk
                if (p < 8) {
                    // ---- stage A: se1 + se2 for pos = ew + 4p ----
                    const int pos = ew + 4 * p;
                    const int slot = half | pos;
                    const int4* hp = (const int4*)(&h1ring[slot][hh * 32]);
                    int4 a0 = hp[0], a1 = hp[1], a2i = hp[2], a3 = hp[3];
                    h2 hv[16] = { I2H(a0.x), I2H(a0.y), I2H(a0.z), I2H(a0.w),
                                  I2H(a1.x), I2H(a1.y), I2H(a1.z), I2H(a1.w),
                                  I2H(a2i.x), I2H(a2i.y), I2H(a2i.z), I2H(a2i.w),
                                  I2H(a3.x), I2H(a3.y), I2H(a3.z), I2H(a3.w) };
                    float acc = 0.f;
                    #pragma unroll
                    for (int k = 0; k < 16; ++k) dot2(acc, w1h[k], hv[k]);
                    acc += __shfl_xor(acc, 32);
                    float se1v = fmaxf(acc + seb1r, 0.f);
                    if (hh == 0) se1b[ew][jj] = (_Float16)se1v;
                    LGKM0();
                    const int4* sp = (const int4*)(&se1b[ew][hh * 16]);
                    int4 s0 = sp[0], s1 = sp[1];
                    h2 sv[8] = { I2H(s0.x), I2H(s0.y), I2H(s0.z), I2H(s0.w),
                                 I2H(s1.x), I2H(s1.y), I2H(s1.z), I2H(s1.w) };
                    float a2 = 0.f;
                    #pragma unroll
                    for (int k = 0; k < 8; ++k) dot2(a2, w2h[k], sv[k]);
                    a2 += __shfl_xor(a2, 32);
                    if (hh == 0) ssb[pos][jj] = (_Float16)(a2 + seb2r);
                } else if (p < 16) {
                    // ---- stage B: dr1 + dr2 + dr3 for pos = ew + 4(p-8) ----
                    const int pos = ew + 4 * (p - 8);
                    const int slot = half | pos;
                    const float ea_ = phys_s[2], la_ = phys_s[3];
                    const int4* xp = (const int4*)(&ssb[pos][0]);
                    int4 x0 = xp[0], x1 = xp[1], x2 = xp[2], x3 = xp[3];
                    h2 xv[16] = { I2H(x0.x), I2H(x0.y), I2H(x0.z), I2H(x0.w),
                                  I2H(x1.x), I2H(x1.y), I2H(x1.z), I2H(x1.w),
                                  I2H(x2.x), I2H(x2.y), I2H(x2.z), I2H(x2.w),
                                  I2H(x3.x), I2H(x3.y), I2H(x3.z), I2H(x3.w) };
                    float acc = 0.f;
                    #pragma unroll
                    for (int k = 0; k < 16; ++k) dot2(acc, wd1h[k], xv[k]);
                    acc += wt0 * tempc[slot] + wt1 * ea_ + wt2 * la_;
                    float d1 = fmaxf(acc + bb1, 0.f);
                    dr1b[ew][lane] = (_Float16)d1;
                    LGKM0();
                    const int4* dp = (const int4*)(&dr1b[ew][hh * 32]);
                    int4 d0 = dp[0], d1i = dp[1], d2 = dp[2], d3 = dp[3];
                    h2 dv[16] = { I2H(d0.x), I2H(d0.y), I2H(d0.z), I2H(d0.w),
                                  I2H(d1i.x), I2H(d1i.y), I2H(d1i.z), I2H(d1i.w),
                                  I2H(d2.x), I2H(d2.y), I2H(d2.z), I2H(d2.w),
                                  I2H(d3.x), I2H(d3.y), I2H(d3.z), I2H(d3.w) };
                    float a2 = 0.f;
                    #pragma unroll
                    for (int k = 0; k < 16; ++k) dot2(a2, wd2h[k], dv[k]);
                    a2 += __shfl_xor(a2, 32);
                    float tt = w3r * fmaxf(a2 + bb2, 0.f);
                    float sum = wsum64_(tt);           // each jj counted twice
                    float deg = 0.5f * sum + drb3r;
                    if (lane == 0) { degb[pos] = deg; outD[32 * c + pos] = deg; }
                } else if (p == 16) {
                    // ---- stage C: health scan (wave 4, clamp-affine scan) ----
                    if (ew == 0) {
                        const int t = lane;
                        const float Af = phys_s[0], ne = phys_s[1];
                        float a_ = 0.f, l_ = -1e30f, u_ = 1e30f;
                        if (t < 32) {
                            float dg = degb[t];
                            float tK = tempc[half | t] + 273.15f;
                            float arr = Af * __expf(ne * rcpf_(tK));
                            a_ = -(0.7f * dg + 0.3f * arr);
                            l_ = 0.f; u_ = 1.f;
                        }
                        #pragma unroll
                        for (int d = 1; d < 32; d <<= 1) {
                            float pa = __shfl_up(a_, d);
                            float pl = __shfl_up(l_, d);
                            float pu = __shfl_up(u_, d);
                            if (t >= d && t < 32) {
                                float na = pa + a_;
                                float nl = fminf(fmaxf(pl + a_, l_), u_);
                                float nu = fminf(fmaxf(pu + a_, l_), u_);
                                a_ = na; l_ = nl; u_ = nu;
                            }
                        }
                        float hval = fminf(fmaxf(hst + a_, l_), u_);
                        if (t < 32) { hltb[t] = hval; outH[32 * c + t] = hval; }
                        float a31 = __shfl(a_, 31), l31 = __shfl(l_, 31), u31 = __shfl(u_, 31);
                        hst = fminf(fmaxf(hst + a31, l31), u31);
                    }
                } else if (p < 25) {
                    // ---- stage D: rul head for pos = ew + 4(p-17) ----
                    const int pos = ew + 4 * (p - 17);
                    const int4* xp = (const int4*)(&ssb[pos][hh * 16]);
                    int4 x0 = xp[0], x1 = xp[1];
                    h2 xv[8] = { I2H(x0.x), I2H(x0.y), I2H(x0.z), I2H(x0.w),
                                 I2H(x1.x), I2H(x1.y), I2H(x1.z), I2H(x1.w) };
                    float acc = 0.f;
                    #pragma unroll
                    for (int k = 0; k < 8; ++k) dot2(acc, wr1h[k], xv[k]);
                    acc += __shfl_xor(acc, 32);
                    float a = acc + brD + whc * hltb[pos];
                    float pp = w2rD * fmaxf(a, 0.f);
                    float sum = wsum64_(pp);
                    if (lane == 0) outR[32 * c + pos] = fmaxf(0.5f * sum + rub2r, 0.f);
                }
            }
            __syncthreads();
        }
    }
}

extern "C" void kernel_launch(void* const* d_in, const int* in_sizes, int n_in,
                              void* d_out, int out_size, void* d_ws, size_t ws_size,
                              hipStream_t stream) {
    const float* ts   = (const float*)d_in[0];
    const float* sf   = (const float*)d_in[1];
    const float* Wih0 = (const float*)d_in[2];
    const float* Whh0 = (const float*)d_in[3];
    const float* bih0 = (const float*)d_in[4];
    const float* bhh0 = (const float*)d_in[5];
    const float* Wih1 = (const float*)d_in[6];
    const float* Whh1 = (const float*)d_in[7];
    const float* bih1 = (const float*)d_in[8];
    const float* bhh1 = (const float*)d_in[9];
    const float* seW1 = (const float*)d_in[10];
    const float* seb1 = (const float*)d_in[11];
    const float* seW2 = (const float*)d_in[12];
    const float* seb2 = (const float*)d_in[13];
    const float* pbW1 = (const float*)d_in[14];
    const float* pbb1 = (const float*)d_in[15];
    const float* pbW2 = (const float*)d_in[16];
    const float* pbb2 = (const float*)d_in[17];
    const float* pbW3 = (const float*)d_in[18];
    const float* pbb3 = (const float*)d_in[19];
    const float* drW1 = (const float*)d_in[20];
    const float* drb1 = (const float*)d_in[21];
    const float* drW2 = (const float*)d_in[22];
    const float* drb2 = (const float*)d_in[23];
    const float* drW3 = (const float*)d_in[24];
    const float* drb3 = (const float*)d_in[25];
    const float* ruW1 = (const float*)d_in[26];
    const float* rub1 = (const float*)d_in[27];
    const float* ruW2 = (const float*)d_in[28];
    const float* rub2 = (const float*)d_in[29];
    float* out = (float*)d_out;

    fused_rul_kernel<<<dim3(Bn), dim3(NT), 0, stream>>>(
        ts, sf, Wih0, Whh0, bih0, bhh0, Wih1, Whh1, bih1, bhh1,
        seW1, seb1, seW2, seb2, pbW1, pbb1, pbW2, pbb2, pbW3, pbb3,
        drW1, drb1, drW2, drb2, drW3, drb3, ruW1, rub1, ruW2, rub2, out);
}

// Round 11
// 1144.954 us; speedup vs baseline: 2.1319x; 1.5778x over previous
//
#include <hip/hip_runtime.h>

// PhysicsRULModel fully-fused kernel for MI355X (gfx950).  R11.
// grid = 256 x 512 (1 block/CU, 8 waves). INTERVAL PIPELINE:
// barriers every 16 LSTM steps (135 total vs R10's 2081). Within an
// interval each wave advances autonomously (lgkmcnt self-sync only).
// Full-row ownership (lane = unit, 4 whole 64-col gate rows = 128 f16
// VGPRs/wave): no cross-lane reduction, no redundant activations.
//   wave 0: L0 (Whh0) self-recurrent; h0 -> h0r ring (f16)
//   wave 1: L1-ih (Wih1) on h0r (lag 1 interval) -> g1r ring (f32 partials)
//   wave 2: L1-hh (Whh1) + combine, self-recurrent h1 -> h1r ring (f16)
//   wave 3: physics MLP (pre-loop) + health clamp-affine scan (lag 5)
//   waves 4-7: epilogue stages A (se1+se2, lag 3), B (dr1+dr2+dr3, lag 4),
//              D (rul, lag 6); resident f16 weights (R10's).
// Every producer ring-window is exactly one barrier-separated interval
// ahead of its consumer; all ring read/write windows disjoint mod ring size
// (h0r/h1r/ssb: 64 slots; g1r/degb/hltb: 32).

#define Bn 256
#define Tn 2048
#define NT 512
#define NI 134

typedef _Float16 h2 __attribute__((ext_vector_type(2)));
union HU { int i; h2 h; };

__device__ __forceinline__ h2 I2H(int v) { HU u; u.i = v; return u.h; }
__device__ __forceinline__ h2 F2H2(float a, float b) { h2 r; r.x = (_Float16)a; r.y = (_Float16)b; return r; }
__device__ __forceinline__ float rcpf_(float x) { return __builtin_amdgcn_rcpf(x); }
__device__ __forceinline__ float sigf_(float x) { return rcpf_(1.f + __expf(-x)); }
__device__ __forceinline__ float tanhf2_(float x) {
    float e = __expf(2.0f * x);
    return 1.0f - 2.0f * rcpf_(e + 1.0f);
}
__device__ __forceinline__ void dot2(float& acc, h2 w, h2 x) {
    asm("v_dot2_f32_f16 %0, %1, %2, %0" : "+v"(acc) : "v"(w), "v"(x));
}
#define DPPF(v, ctrl) __int_as_float(__builtin_amdgcn_update_dpp(0, __float_as_int(v), (ctrl), 0xF, 0xF, true))
#define LGKM0() asm volatile("s_waitcnt lgkmcnt(0)" ::: "memory")
#define UNP4(h, o, r) { h[(o)] = I2H((r).x); h[(o)+1] = I2H((r).y); h[(o)+2] = I2H((r).z); h[(o)+3] = I2H((r).w); }

__device__ __forceinline__ float wsum64_(float v) {
    v += DPPF(v, 0xB1); v += DPPF(v, 0x4E);
    v += __shfl_xor(v, 4); v += __shfl_xor(v, 8);
    v += __shfl_xor(v, 16); v += __shfl_xor(v, 32);
    return v;
}

__global__ __launch_bounds__(512, 1)
void fused_rul_kernel(
    const float* __restrict__ ts,   const float* __restrict__ sf,
    const float* __restrict__ Wih0, const float* __restrict__ Whh0,
    const float* __restrict__ bih0, const float* __restrict__ bhh0,
    const float* __restrict__ Wih1, const float* __restrict__ Whh1,
    const float* __restrict__ bih1, const float* __restrict__ bhh1,
    const float* __restrict__ seW1, const float* __restrict__ seb1,
    const float* __restrict__ seW2, const float* __restrict__ seb2,
    const float* __restrict__ pbW1, const float* __restrict__ pbb1,
    const float* __restrict__ pbW2, const float* __restrict__ pbb2,
    const float* __restrict__ pbW3, const float* __restrict__ pbb3,
    const float* __restrict__ drW1, const float* __restrict__ drb1,
    const float* __restrict__ drW2, const float* __restrict__ drb2,
    const float* __restrict__ drW3, const float* __restrict__ drb3,
    const float* __restrict__ ruW1, const float* __restrict__ rub1,
    const float* __restrict__ ruW2, const float* __restrict__ rub2,
    float* __restrict__ out)
{
    const int tid  = threadIdx.x;
    const int b    = blockIdx.x;
    const int lane = tid & 63;
    const int w    = tid >> 6;                        // wave 0..7

    // ---- LDS rings (~53 KB) ----
    __shared__ __align__(16) _Float16 h0r[64][64];    // h0(t), slot t&63
    __shared__ __align__(16) _Float16 h1r[64][64];    // h1(t), slot t&63
    __shared__ __align__(16) float4   g1r[32][64];    // L1 ih partials, slot t&31
    __shared__ __align__(16) _Float16 ssb[64][32];    // system_states, slot t&63
    __shared__ __align__(16) _Float16 se1b[4][32];    // wave-private
    __shared__ __align__(16) _Float16 dr1b[4][64];    // wave-private
    __shared__ float degb[32];                        // slot t&31
    __shared__ float hltb[32];                        // slot t&31
    __shared__ float phys_s[4];                       // [A, -Ea*1000/R, Ea, logA]

    const float* tsb = ts + (size_t)b * Tn * 2;
    float* outR = out + (size_t)b * Tn;
    float* outD = out + (size_t)Bn * Tn + (size_t)b * Tn;
    float* outH = out + 2 * (size_t)Bn * Tn + (size_t)b * Tn;

    if (w == 0) {
        // ================= wave 0: L0 recurrence =================
        h2 wf[128]; float b0[4], wx[4], wy[4];
        #pragma unroll
        for (int g = 0; g < 4; ++g) {
            const int row = (g << 6) + lane;
            const float* r = Whh0 + row * 64;
            #pragma unroll
            for (int k = 0; k < 32; ++k) wf[g * 32 + k] = F2H2(r[2 * k], r[2 * k + 1]);
            b0[g] = bih0[row] + bhh0[row];
            wx[g] = Wih0[row * 2]; wy[g] = Wih0[row * 2 + 1];
        }
        h2 hv[32];
        #pragma unroll
        for (int k = 0; k < 32; ++k) hv[k] = F2H2(0.f, 0.f);
        float c0 = 0.f;
        __syncthreads();
        for (int I = 0; I < NI; ++I) {
            const int base = I << 4;
            if (base < Tn) {
                float2 xp = make_float2(0.f, 0.f);
                if (lane < 16) xp = *(const float2*)(tsb + 2 * (base + lane));
                #pragma unroll 1
                for (int j = 0; j < 16; ++j) {
                    const int u = base + j;
                    float a0 = 0, a1 = 0, a2 = 0, a3 = 0, a4 = 0, a5 = 0, a6 = 0, a7 = 0;
                    #pragma unroll
                    for (int k = 0; k < 16; ++k) {
                        dot2(a0, wf[k],       hv[k]); dot2(a4, wf[16 + k],  hv[16 + k]);
                        dot2(a1, wf[32 + k],  hv[k]); dot2(a5, wf[48 + k],  hv[16 + k]);
                        dot2(a2, wf[64 + k],  hv[k]); dot2(a6, wf[80 + k],  hv[16 + k]);
                        dot2(a3, wf[96 + k],  hv[k]); dot2(a7, wf[112 + k], hv[16 + k]);
                    }
                    float sx = __shfl(xp.x, j), sy = __shfl(xp.y, j);
                    float pi = a0 + a4 + b0[0] + wx[0] * sx + wy[0] * sy;
                    float pf = a1 + a5 + b0[1] + wx[1] * sx + wy[1] * sy;
                    float pg = a2 + a6 + b0[2] + wx[2] * sx + wy[2] * sy;
                    float po = a3 + a7 + b0[3] + wx[3] * sx + wy[3] * sy;
                    float ai = sigf_(pi), af = sigf_(pf), ag = tanhf2_(pg), ao = sigf_(po);
                    c0 = fmaf(af, c0, ai * ag);
                    float h0n = ao * tanhf2_(c0);
                    h0r[u & 63][lane] = (_Float16)h0n;
                    LGKM0();
                    const int4* rp = (const int4*)&h0r[u & 63][0];
                    int4 r0 = rp[0], r1 = rp[1], r2 = rp[2], r3 = rp[3];
                    int4 r4 = rp[4], r5 = rp[5], r6 = rp[6], r7 = rp[7];
                    UNP4(hv, 0, r0);  UNP4(hv, 4, r1);  UNP4(hv, 8, r2);  UNP4(hv, 12, r3);
                    UNP4(hv, 16, r4); UNP4(hv, 20, r5); UNP4(hv, 24, r6); UNP4(hv, 28, r7);
                }
            }
            __syncthreads();
        }
    } else if (w == 1) {
        // ================= wave 1: L1 input-to-hidden =================
        h2 wf[128];
        #pragma unroll
        for (int g = 0; g < 4; ++g) {
            const float* r = Wih1 + ((g << 6) + lane) * 64;
            #pragma unroll
            for (int k = 0; k < 32; ++k) wf[g * 32 + k] = F2H2(r[2 * k], r[2 * k + 1]);
        }
        __syncthreads();
        for (int I = 0; I < NI; ++I) {
            const int tb = (I << 4) - 16;
            if (tb >= 0 && tb < Tn) {
                #pragma unroll 1
                for (int j = 0; j < 16; ++j) {
                    const int t = tb + j;
                    const int4* rp = (const int4*)&h0r[t & 63][0];
                    int4 r0 = rp[0], r1 = rp[1], r2 = rp[2], r3 = rp[3];
                    int4 r4 = rp[4], r5 = rp[5], r6 = rp[6], r7 = rp[7];
                    h2 hv[32];
                    UNP4(hv, 0, r0);  UNP4(hv, 4, r1);  UNP4(hv, 8, r2);  UNP4(hv, 12, r3);
                    UNP4(hv, 16, r4); UNP4(hv, 20, r5); UNP4(hv, 24, r6); UNP4(hv, 28, r7);
                    float a0 = 0, a1 = 0, a2 = 0, a3 = 0, a4 = 0, a5 = 0, a6 = 0, a7 = 0;
                    #pragma unroll
                    for (int k = 0; k < 16; ++k) {
                        dot2(a0, wf[k],       hv[k]); dot2(a4, wf[16 + k],  hv[16 + k]);
                        dot2(a1, wf[32 + k],  hv[k]); dot2(a5, wf[48 + k],  hv[16 + k]);
                        dot2(a2, wf[64 + k],  hv[k]); dot2(a6, wf[80 + k],  hv[16 + k]);
                        dot2(a3, wf[96 + k],  hv[k]); dot2(a7, wf[112 + k], hv[16 + k]);
                    }
                    g1r[t & 31][lane] = make_float4(a0 + a4, a1 + a5, a2 + a6, a3 + a7);
                }
            }
            __syncthreads();
        }
    } else if (w == 2) {
        // ================= wave 2: L1 hidden + combine =================
        h2 wf[128]; float b1[4];
        #pragma unroll
        for (int g = 0; g < 4; ++g) {
            const int row = (g << 6) + lane;
            const float* r = Whh1 + row * 64;
            #pragma unroll
            for (int k = 0; k < 32; ++k) wf[g * 32 + k] = F2H2(r[2 * k], r[2 * k + 1]);
            b1[g] = bih1[row] + bhh1[row];
        }
        h2 hv[32];
        #pragma unroll
        for (int k = 0; k < 32; ++k) hv[k] = F2H2(0.f, 0.f);
        float c1 = 0.f;
        __syncthreads();
        for (int I = 0; I < NI; ++I) {
            const int tb = (I << 4) - 32;
            if (tb >= 0 && tb < Tn) {
                #pragma unroll 1
                for (int j = 0; j < 16; ++j) {
                    const int t = tb + j;
                    float4 p = g1r[t & 31][lane];
                    float a0 = 0, a1 = 0, a2 = 0, a3 = 0, a4 = 0, a5 = 0, a6 = 0, a7 = 0;
                    #pragma unroll
                    for (int k = 0; k < 16; ++k) {
                        dot2(a0, wf[k],       hv[k]); dot2(a4, wf[16 + k],  hv[16 + k]);
                        dot2(a1, wf[32 + k],  hv[k]); dot2(a5, wf[48 + k],  hv[16 + k]);
                        dot2(a2, wf[64 + k],  hv[k]); dot2(a6, wf[80 + k],  hv[16 + k]);
                        dot2(a3, wf[96 + k],  hv[k]); dot2(a7, wf[112 + k], hv[16 + k]);
                    }
                    float pi = p.x + a0 + a4 + b1[0];
                    float pf = p.y + a1 + a5 + b1[1];
                    float pg = p.z + a2 + a6 + b1[2];
                    float po = p.w + a3 + a7 + b1[3];
                    float ai = sigf_(pi), af = sigf_(pf), ag = tanhf2_(pg), ao = sigf_(po);
                    c1 = fmaf(af, c1, ai * ag);
                    float h1n = ao * tanhf2_(c1);
                    h1r[t & 63][lane] = (_Float16)h1n;
                    LGKM0();
                    const int4* rp = (const int4*)&h1r[t & 63][0];
                    int4 r0 = rp[0], r1 = rp[1], r2 = rp[2], r3 = rp[3];
                    int4 r4 = rp[4], r5 = rp[5], r6 = rp[6], r7 = rp[7];
                    UNP4(hv, 0, r0);  UNP4(hv, 4, r1);  UNP4(hv, 8, r2);  UNP4(hv, 12, r3);
                    UNP4(hv, 16, r4); UNP4(hv, 20, r5); UNP4(hv, 24, r6); UNP4(hv, 28, r7);
                }
            }
            __syncthreads();
        }
    } else if (w == 3) {
        // ================= wave 3: physics + health scan =================
        if (lane == 0) {
            float p1[32];
            for (int o = 0; o < 32; ++o) {
                float a = pbb1[o];
                for (int k = 0; k < 3; ++k) a += pbW1[o * 3 + k] * sf[b * 3 + k];
                p1[o] = fmaxf(a, 0.f);
            }
            float p2[16];
            for (int o = 0; o < 16; ++o) {
                float a = pbb2[o];
                for (int k = 0; k < 32; ++k) a += pbW2[o * 32 + k] * p1[k];
                p2[o] = fmaxf(a, 0.f);
            }
            float Ea = pbb3[0], lA = pbb3[1];
            for (int k = 0; k < 16; ++k) { Ea += pbW3[k] * p2[k]; lA += pbW3[16 + k] * p2[k]; }
            phys_s[0] = __expf(lA);
            phys_s[1] = -Ea * 1000.0f / 8.314f;
            phys_s[2] = Ea;
            phys_s[3] = lA;
        }
        float hst = 1.0f;
        __syncthreads();
        for (int I = 0; I < NI; ++I) {
            const int t0s = (I << 4) - 80;
            if (t0s >= 0 && t0s < Tn) {
                const int t = lane;
                const float Af = phys_s[0], ne = phys_s[1];
                float a_ = 0.f, l_ = -1e30f, u_ = 1e30f;
                if (t < 16) {
                    float dg = degb[(t0s + t) & 31];
                    float tK = tsb[2 * (t0s + t)] + 273.15f;
                    float arr = Af * __expf(ne * rcpf_(tK));
                    a_ = -(0.7f * dg + 0.3f * arr);
                    l_ = 0.f; u_ = 1.f;
                }
                #pragma unroll
                for (int d = 1; d < 16; d <<= 1) {
                    float pa = __shfl_up(a_, d);
                    float pl = __shfl_up(l_, d);
                    float pu = __shfl_up(u_, d);
                    if (t >= d && t < 16) {
                        float na = pa + a_;
                        float nl = fminf(fmaxf(pl + a_, l_), u_);
                        float nu = fminf(fmaxf(pu + a_, l_), u_);
                        a_ = na; l_ = nl; u_ = nu;
                    }
                }
                float hval = fminf(fmaxf(hst + a_, l_), u_);
                if (t < 16) { hltb[(t0s + t) & 31] = hval; outH[t0s + t] = hval; }
                hst = __shfl(hval, 15);
            }
            __syncthreads();
        }
    } else {
        // ================= waves 4-7: epilogue stages A/B/D =================
        const int ew = w - 4, jj = lane & 31, hh = lane >> 5;
        h2 w1h[16], w2h[8], wd1h[16], wd2h[16], wr1h[8];
        float wt0, wt1, wt2, bb1, seb1r, seb2r, bb2, w3r, whc, brD, w2rD, drb3r, rub2r;
        {
            const float* r = seW1 + jj * 64 + hh * 32;
            #pragma unroll
            for (int k = 0; k < 16; ++k) w1h[k] = F2H2(r[2 * k], r[2 * k + 1]);
            r = seW2 + jj * 32 + hh * 16;
            #pragma unroll
            for (int k = 0; k < 8; ++k) w2h[k] = F2H2(r[2 * k], r[2 * k + 1]);
            r = drW1 + lane * 35;
            #pragma unroll
            for (int k = 0; k < 16; ++k) wd1h[k] = F2H2(r[2 * k], r[2 * k + 1]);
            wt0 = r[32]; wt1 = r[33]; wt2 = r[34];
            r = drW2 + jj * 64 + hh * 32;
            #pragma unroll
            for (int k = 0; k < 16; ++k) wd2h[k] = F2H2(r[2 * k], r[2 * k + 1]);
            r = ruW1 + jj * 33 + hh * 16;
            #pragma unroll
            for (int k = 0; k < 8; ++k) wr1h[k] = F2H2(r[2 * k], r[2 * k + 1]);
            seb1r = seb1[jj]; seb2r = seb2[jj];
            bb1 = drb1[lane]; bb2 = drb2[jj]; w3r = drW3[jj];
            whc = ruW1[jj * 33 + 32]; brD = rub1[jj]; w2rD = ruW2[jj];
            drb3r = drb3[0]; rub2r = rub2[0];
        }
        __syncthreads();
        for (int I = 0; I < NI; ++I) {
            const int Abase = (I << 4) - 48;
            const int Bbase = (I << 4) - 64;
            const int Dbase = (I << 4) - 96;
            // temp prefetch for stage B (hide VMEM latency behind stage A)
            float tpre[4];
            if (Bbase >= 0 && Bbase < Tn) {
                #pragma unroll
                for (int i = 0; i < 4; ++i) tpre[i] = tsb[2 * (Bbase + (ew << 2) + i)];
            }
            // ---- stage A: se1 + se2 for [Abase, Abase+16) ----
            if (Abase >= 0 && Abase < Tn) {
                #pragma unroll 1
                for (int i = 0; i < 4; ++i) {
                    const int pos = Abase + (ew << 2) + i;
                    const int slot = pos & 63;
                    const int4* hp = (const int4*)(&h1r[slot][hh * 32]);
                    int4 q0 = hp[0], q1 = hp[1], q2 = hp[2], q3 = hp[3];
                    h2 hv16[16];
                    UNP4(hv16, 0, q0); UNP4(hv16, 4, q1); UNP4(hv16, 8, q2); UNP4(hv16, 12, q3);
                    float acc = 0.f;
                    #pragma unroll
                    for (int k = 0; k < 16; ++k) dot2(acc, w1h[k], hv16[k]);
                    acc += __shfl_xor(acc, 32);
                    float se1v = fmaxf(acc + seb1r, 0.f);
                    if (hh == 0) se1b[ew][jj] = (_Float16)se1v;
                    LGKM0();
                    const int4* sp = (const int4*)(&se1b[ew][hh * 16]);
                    int4 s0 = sp[0], s1 = sp[1];
                    h2 sv[8];
                    UNP4(sv, 0, s0); UNP4(sv, 4, s1);
                    float a2 = 0.f;
                    #pragma unroll
                    for (int k = 0; k < 8; ++k) dot2(a2, w2h[k], sv[k]);
                    a2 += __shfl_xor(a2, 32);
                    if (hh == 0) ssb[slot][jj] = (_Float16)(a2 + seb2r);
                }
            }
            // ---- stage B: dr1 + dr2 + dr3 for [Bbase, Bbase+16) ----
            if (Bbase >= 0 && Bbase < Tn) {
                const float ea_ = phys_s[2], la_ = phys_s[3];
                #pragma unroll 1
                for (int i = 0; i < 4; ++i) {
                    const int pos = Bbase + (ew << 2) + i;
                    const int slot = pos & 63;
                    const int4* xp = (const int4*)(&ssb[slot][0]);
                    int4 x0 = xp[0], x1 = xp[1], x2 = xp[2], x3 = xp[3];
                    h2 xv[16];
                    UNP4(xv, 0, x0); UNP4(xv, 4, x1); UNP4(xv, 8, x2); UNP4(xv, 12, x3);
                    float acc = 0.f;
                    #pragma unroll
                    for (int k = 0; k < 16; ++k) dot2(acc, wd1h[k], xv[k]);
                    acc += wt0 * tpre[i] + wt1 * ea_ + wt2 * la_;
                    dr1b[ew][lane] = (_Float16)fmaxf(acc + bb1, 0.f);
                    LGKM0();
                    const int4* dp = (const int4*)(&dr1b[ew][hh * 32]);
                    int4 d0 = dp[0], d1 = dp[1], d2 = dp[2], d3 = dp[3];
                    h2 dv[16];
                    UNP4(dv, 0, d0); UNP4(dv, 4, d1); UNP4(dv, 8, d2); UNP4(dv, 12, d3);
                    float a2 = 0.f;
                    #pragma unroll
                    for (int k = 0; k < 16; ++k) dot2(a2, wd2h[k], dv[k]);
                    a2 += __shfl_xor(a2, 32);
                    float tt = w3r * fmaxf(a2 + bb2, 0.f);
                    float sum = wsum64_(tt);          // each jj counted twice
                    float deg = 0.5f * sum + drb3r;
                    if (lane == 0) { degb[pos & 31] = deg; outD[pos] = deg; }
                }
            }
            // ---- stage D: rul head for [Dbase, Dbase+16) ----
            if (Dbase >= 0 && Dbase < Tn) {
                #pragma unroll 1
                for (int i = 0; i < 4; ++i) {
                    const int pos = Dbase + (ew << 2) + i;
                    const int slot = pos & 63;
                    const int4* xp = (const int4*)(&ssb[slot][hh * 16]);
                    int4 x0 = xp[0], x1 = xp[1];
                    h2 xv[8];
                    UNP4(xv, 0, x0); UNP4(xv, 4, x1);
                    float acc = 0.f;
                    #pragma unroll
                    for (int k = 0; k < 8; ++k) dot2(acc, wr1h[k], xv[k]);
                    acc += __shfl_xor(acc, 32);
                    float a = acc + brD + whc * hltb[pos & 31];
                    float pp = w2rD * fmaxf(a, 0.f);
                    float sum = wsum64_(pp);
                    if (lane == 0) outR[pos] = fmaxf(0.5f * sum + rub2r, 0.f);
                }
            }
            __syncthreads();
        }
    }
}

extern "C" void kernel_launch(void* const* d_in, const int* in_sizes, int n_in,
                              void* d_out, int out_size, void* d_ws, size_t ws_size,
                              hipStream_t stream) {
    const float* ts   = (const float*)d_in[0];
    const float* sf   = (const float*)d_in[1];
    const float* Wih0 = (const float*)d_in[2];
    const float* Whh0 = (const float*)d_in[3];
    const float* bih0 = (const float*)d_in[4];
    const float* bhh0 = (const float*)d_in[5];
    const float* Wih1 = (const float*)d_in[6];
    const float* Whh1 = (const float*)d_in[7];
    const float* bih1 = (const float*)d_in[8];
    const float* bhh1 = (const float*)d_in[9];
    const float* seW1 = (const float*)d_in[10];
    const float* seb1 = (const float*)d_in[11];
    const float* seW2 = (const float*)d_in[12];
    const float* seb2 = (const float*)d_in[13];
    const float* pbW1 = (const float*)d_in[14];
    const float* pbb1 = (const float*)d_in[15];
    const float* pbW2 = (const float*)d_in[16];
    const float* pbb2 = (const float*)d_in[17];
    const float* pbW3 = (const float*)d_in[18];
    const float* pbb3 = (const float*)d_in[19];
    const float* drW1 = (const float*)d_in[20];
    const float* drb1 = (const float*)d_in[21];
    const float* drW2 = (const float*)d_in[22];
    const float* drb2 = (const float*)d_in[23];
    const float* drW3 = (const float*)d_in[24];
    const float* drb3 = (const float*)d_in[25];
    const float* ruW1 = (const float*)d_in[26];
    const float* rub1 = (const float*)d_in[27];
    const float* ruW2 = (const float*)d_in[28];
    const float* rub2 = (const float*)d_in[29];
    float* out = (float*)d_out;

    fused_rul_kernel<<<dim3(Bn), dim3(NT), 0, stream>>>(
        ts, sf, Wih0, Whh0, bih0, bhh0, Wih1, Whh1, bih1, bhh1,
        seW1, seb1, seW2, seb2, pbW1, pbb1, pbW2, pbb2, pbW3, pbb3,
        drW1, drb1, drW2, drb2, drW3, drb3, ruW1, rub1, ruW2, rub2, out);
}